// Round 1
// baseline (140.577 us; speedup 1.0000x reference)
//
#include <hip/hip_runtime.h>
#include <hip/hip_bf16.h>

#define NB 4
#define NN 2048
#define NF 256

using bf16x8 = __attribute__((ext_vector_type(8))) short;
using f32x4  = __attribute__((ext_vector_type(4))) float;

__device__ __forceinline__ short f2bf(float f) {
    unsigned u = __float_as_uint(f);
    u += 0x7fffu + ((u >> 16) & 1u);   // RNE, finite inputs only
    return (short)(u >> 16);
}
__device__ __forceinline__ unsigned enc_ord(float f) {   // order-preserving f32->u32
    unsigned u = __float_as_uint(f);
    return (u & 0x80000000u) ? ~u : (u | 0x80000000u);
}
__device__ __forceinline__ float dec_ord(unsigned u) {
    unsigned i = (u & 0x80000000u) ? (u & 0x7fffffffu) : ~u;
    return __uint_as_float(i);
}

// ---- prep: adj->bitmask (ballot), x->bf16, W->W^T bf16, zero maxfd slots ----
__global__ __launch_bounds__(256) void prep_kernel(
    const float* __restrict__ x, const int* __restrict__ adj, const float* __restrict__ W,
    short* __restrict__ WT, short* __restrict__ xb,
    unsigned long long* __restrict__ adjP, unsigned* __restrict__ maxfd)
{
    const int R3 = (NB*NN*NN)/256;        // 65536 blocks: adj pack
    const int R2 = (NB*NN*NF)/(256*4);    // 2048 blocks: x convert, 4/thread
    const int R1 = (NF*NF)/256;           // 256 blocks: W transpose+convert
    const int blk = blockIdx.x, tid = threadIdx.x;
    if (blk < R3) {
        int idx = blk*256 + tid;
        unsigned long long m = __ballot(adj[idx] > 0);
        if ((tid & 63) == 0) adjP[idx >> 6] = m;   // bit k of word <-> j = base+k
    } else if (blk < R3 + R2) {
        int t = (blk - R3)*256 + tid;
        float4 v = ((const float4*)x)[t];
        short4 o; o.x = f2bf(v.x); o.y = f2bf(v.y); o.z = f2bf(v.z); o.w = f2bf(v.w);
        ((short4*)xb)[t] = o;
    } else if (blk < R3 + R2 + R1) {
        int t = (blk - R3 - R2)*256 + tid;
        int g = t >> 8, f = t & 255;
        WT[t] = f2bf(W[f*NF + g]);        // WT[g][f] = W[f][g]
    } else {
        if (tid < NB) maxfd[tid] = 0u;    // below enc of any finite float
    }
}

// ---- h = x@W via bf16 MFMA; writes hT[b][g][i] (bf16), f_src/f_dst, maxfd ----
// 128 blocks x 256 thr; wave w owns rows m0 = blk*64 + w*16 .. +16, all 256 cols.
__global__ __launch_bounds__(256) void h_kernel(
    const short* __restrict__ xb, const short* __restrict__ WT, const float* __restrict__ a,
    short* __restrict__ hT, float* __restrict__ fsrc, float* __restrict__ fdst,
    unsigned* __restrict__ maxfd)
{
    const int w  = threadIdx.x >> 6;
    const int l  = threadIdx.x & 63;
    const int lr = l & 15, lg = l >> 4;
    const int m0 = blockIdx.x * 64 + w * 16;

    f32x4 acc[16];
    #pragma unroll
    for (int i = 0; i < 16; i++) acc[i] = (f32x4){0.f,0.f,0.f,0.f};

    const short* arow = xb + (size_t)(m0 + lr) * NF;
    #pragma unroll
    for (int k0 = 0; k0 < NF; k0 += 32) {
        bf16x8 af = *(const bf16x8*)(arow + k0 + 8*lg);      // A[m][k]: m=l&15, k=8*(l>>4)+e
        #pragma unroll
        for (int nt = 0; nt < 16; nt++) {
            bf16x8 bf = *(const bf16x8*)(WT + (size_t)(nt*16 + lr)*NF + k0 + 8*lg); // B[k][n] via W^T
            acc[nt] = __builtin_amdgcn_mfma_f32_16x16x32_bf16(af, bf, acc[nt], 0, 0, 0);
        }
    }

    const int b = m0 / NN;
    const int iloc = (m0 % NN) + lg*4;     // D row = (l>>4)*4 + r  (verified m89 layout)

    float fsv[4] = {0,0,0,0}, fdv[4] = {0,0,0,0};
    #pragma unroll
    for (int nt = 0; nt < 16; nt++) {
        int g = nt*16 + lr;                // D col = l&15
        float as = a[g], ad = a[NF + g];
        short4 hv;
        hv.x = f2bf(acc[nt][0]); hv.y = f2bf(acc[nt][1]);
        hv.z = f2bf(acc[nt][2]); hv.w = f2bf(acc[nt][3]);
        *(short4*)(hT + ((size_t)(b*NF + g))*NN + iloc) = hv;   // transposed store, 8B
        #pragma unroll
        for (int r = 0; r < 4; r++) { fsv[r] += acc[nt][r]*as; fdv[r] += acc[nt][r]*ad; }
    }
    #pragma unroll
    for (int mask = 1; mask < 16; mask <<= 1) {
        #pragma unroll
        for (int r = 0; r < 4; r++) {
            fsv[r] += __shfl_xor(fsv[r], mask);
            fdv[r] += __shfl_xor(fdv[r], mask);
        }
    }
    if (lr == 0) {
        #pragma unroll
        for (int r = 0; r < 4; r++) {
            fsrc[m0 + lg*4 + r] = fsv[r];
            fdst[m0 + lg*4 + r] = fdv[r];
        }
    }
    float wm = fmaxf(fmaxf(fdv[0], fdv[1]), fmaxf(fdv[2], fdv[3]));
    wm = fmaxf(wm, __shfl_xor(wm, 16));
    wm = fmaxf(wm, __shfl_xor(wm, 32));
    if (l == 0) atomicMax(maxfd + b, enc_ord(wm));
}

// ---- fused masked-softmax + att@h + elu ----
// 256 blocks x 512 thr. Block: b = bi>>6, rows i0=(bi&63)*32 .. +32.
// Wave w: ig=w>>2 picks 16-row half, f0=(w&3)*64 picks 64-col slice (4 MFMA n-tiles).
// p computed in-register (A-frag), B-frag = 16B contiguous loads from hT[b][f][j].
__global__ __launch_bounds__(512) void gat_fused(
    const short* __restrict__ hT, const unsigned char* __restrict__ adjB,
    const float* __restrict__ fsrc, const float* __restrict__ fdst,
    const unsigned* __restrict__ maxfd, float* __restrict__ out)
{
    const int w  = threadIdx.x >> 6;
    const int l  = threadIdx.x & 63;
    const int lr = l & 15, lg = l >> 4;
    const int bi = blockIdx.x;
    const int b  = bi >> 6;
    const int i0 = (bi & 63) * 32;
    const int ig = w >> 2;
    const int f0 = (w & 3) * 64;

    const int i = i0 + ig*16 + lr;                    // A-frag row
    const float fs = fsrc[b*NN + i];
    const float M  = fmaxf(fs + dec_ord(maxfd[b]), 0.f);   // safe upper bound on row max
    const float* fdb = fdst + b*NN;
    const unsigned char* arow = adjB + (size_t)(b*NN + i) * (NN/8);
    const short* hTb = hT + (size_t)b * NF * NN;

    f32x4 acc[4];
    #pragma unroll
    for (int t = 0; t < 4; t++) acc[t] = (f32x4){0.f,0.f,0.f,0.f};
    float lsum = 0.f;

    for (int j0 = 0; j0 < NN; j0 += 32) {
        const int jb = j0 + 8*lg;                     // this lane's 8 k-slots
        unsigned m8 = arow[jb >> 3];
        float4 fd0 = *(const float4*)(fdb + jb);
        float4 fd1 = *(const float4*)(fdb + jb + 4);
        float fda[8] = {fd0.x, fd0.y, fd0.z, fd0.w, fd1.x, fd1.y, fd1.z, fd1.w};
        bf16x8 af;
        #pragma unroll
        for (int e = 0; e < 8; e++) {
            float ev = fmaxf(fs + fda[e], 0.f);       // relu score
            float pe = ((m8 >> e) & 1u) ? __expf(ev - M) : 0.f;
            lsum += pe;
            af[e] = f2bf(pe);
        }
        #pragma unroll
        for (int nt = 0; nt < 4; nt++) {
            bf16x8 bf = *(const bf16x8*)(hTb + (size_t)(f0 + nt*16 + lr)*NN + jb);
            acc[nt] = __builtin_amdgcn_mfma_f32_16x16x32_bf16(af, bf, acc[nt], 0, 0, 0);
        }
    }

    lsum += __shfl_xor(lsum, 16);                     // sum over the 4 j-slices of row i
    lsum += __shfl_xor(lsum, 32);

    __shared__ float ls[32];
    if ((w & 3) == 0 && l < 16) ls[ig*16 + l] = lsum; // waves 0 and 4 publish row sums
    __syncthreads();

    #pragma unroll
    for (int r = 0; r < 4; r++) {
        float lv = ls[ig*16 + lg*4 + r];
        float rv = lv > 0.f ? 1.f / lv : 0.f;
        #pragma unroll
        for (int nt = 0; nt < 4; nt++) {
            float v = acc[nt][r] * rv;
            v = v > 0.f ? v : expm1f(v);              // elu
            out[(size_t)(b*NN + i0 + ig*16 + lg*4 + r)*NF + f0 + nt*16 + lr] = v;
        }
    }
}

extern "C" void kernel_launch(void* const* d_in, const int* in_sizes, int n_in,
                              void* d_out, int out_size, void* d_ws, size_t ws_size,
                              hipStream_t stream) {
    const float* x   = (const float*)d_in[0];
    const int*   adj = (const int*)d_in[1];
    const float* W   = (const float*)d_in[2];
    const float* a   = (const float*)d_in[3];
    float* out = (float*)d_out;
    char* ws = (char*)d_ws;

    short* WT = (short*)(ws);                                   // 128 KB
    short* xb = (short*)(ws + 0x20000);                         // 4 MB
    unsigned long long* adjP = (unsigned long long*)(ws + 0x420000); // 2 MB
    short* hT = (short*)(ws + 0x620000);                        // 4 MB
    float* fsrc = (float*)(ws + 0xA20000);                      // 32 KB
    float* fdst = (float*)(ws + 0xA28000);                      // 32 KB
    unsigned* maxfd = (unsigned*)(ws + 0xA30000);               // 16 B

    const int prep_blocks = (NB*NN*NN)/256 + (NB*NN*NF)/1024 + (NF*NF)/256 + 1;
    prep_kernel<<<prep_blocks, 256, 0, stream>>>(x, adj, W, WT, xb, adjP, maxfd);
    h_kernel<<<(NB*NN)/64, 256, 0, stream>>>(xb, WT, a, hT, fsrc, fdst, maxfd);
    gat_fused<<<NB*(NN/32), 512, 0, stream>>>(hT, (const unsigned char*)adjP,
                                              fsrc, fdst, maxfd, out);
}

// Round 2
// 120.029 us; speedup vs baseline: 1.1712x; 1.1712x over previous
//
#include <hip/hip_runtime.h>
#include <hip/hip_bf16.h>

#define NB 4
#define NN 2048
#define NF 256

using bf16x8 = __attribute__((ext_vector_type(8))) short;
using f32x4  = __attribute__((ext_vector_type(4))) float;

__device__ __forceinline__ short f2bf(float f) {
    unsigned u = __float_as_uint(f);
    u += 0x7fffu + ((u >> 16) & 1u);   // RNE, finite inputs only
    return (short)(u >> 16);
}
__device__ __forceinline__ unsigned enc_ord(float f) {   // order-preserving f32->u32
    unsigned u = __float_as_uint(f);
    return (u & 0x80000000u) ? ~u : (u | 0x80000000u);
}
__device__ __forceinline__ float dec_ord(unsigned u) {
    unsigned i = (u & 0x80000000u) ? (u & 0x7fffffffu) : ~u;
    return __uint_as_float(i);
}

// ---- prep: adj->bitmask (ballot), W->W^T bf16, zero maxfd ----
__global__ __launch_bounds__(256) void prep_kernel(
    const int* __restrict__ adj, const float* __restrict__ W,
    short* __restrict__ WT, unsigned long long* __restrict__ adjP,
    unsigned* __restrict__ maxfd)
{
    const int R3 = (NB*NN*NN)/256;        // 65536 blocks: adj pack
    const int R1 = (NF*NF)/256;           // 256 blocks: W transpose+convert
    const int blk = blockIdx.x, tid = threadIdx.x;
    if (blk < R3) {
        int idx = blk*256 + tid;
        unsigned long long m = __ballot(adj[idx] > 0);
        if ((tid & 63) == 0) adjP[idx >> 6] = m;
    } else if (blk < R3 + R1) {
        int t = (blk - R3)*256 + tid;
        int g = t >> 8, f = t & 255;
        WT[t] = f2bf(W[f*NF + g]);        // WT[g][f] = W[f][g]
    } else if (tid < NB) {
        maxfd[tid] = 0u;
    }
}

// ---- h = x@W (bf16 MFMA); hT[b][g][i] bf16, f_src/f_dst, per-batch max(fdst) ----
// 512 blocks x 256 thr. Block: 16 rows. Wave w: 64-col slice (4 n-tiles), full K.
__global__ __launch_bounds__(256,4) void h_kernel(
    const float* __restrict__ x, const short* __restrict__ WT, const float* __restrict__ a,
    short* __restrict__ hT, float* __restrict__ fsrc, float* __restrict__ fdst,
    unsigned* __restrict__ maxfd)
{
    __shared__ float fs_l[16], fd_l[16];
    const int w  = threadIdx.x >> 6;
    const int l  = threadIdx.x & 63;
    const int lr = l & 15, lg = l >> 4;
    const int b  = blockIdx.x >> 7;
    const int ib = (blockIdx.x & 127) * 16;

    if (threadIdx.x < 16) { fs_l[threadIdx.x] = 0.f; fd_l[threadIdx.x] = 0.f; }
    __syncthreads();

    f32x4 acc[4];
    #pragma unroll
    for (int t = 0; t < 4; t++) acc[t] = (f32x4){0.f,0.f,0.f,0.f};

    const float* xrow = x + (size_t)(b*NN + ib + lr) * NF;
    #pragma unroll
    for (int k0 = 0; k0 < NF; k0 += 32) {
        float4 v0 = *(const float4*)(xrow + k0 + 8*lg);
        float4 v1 = *(const float4*)(xrow + k0 + 8*lg + 4);
        bf16x8 af;
        af[0]=f2bf(v0.x); af[1]=f2bf(v0.y); af[2]=f2bf(v0.z); af[3]=f2bf(v0.w);
        af[4]=f2bf(v1.x); af[5]=f2bf(v1.y); af[6]=f2bf(v1.z); af[7]=f2bf(v1.w);
        #pragma unroll
        for (int nt = 0; nt < 4; nt++) {
            int g = w*64 + nt*16 + lr;
            bf16x8 bf = *(const bf16x8*)(WT + (size_t)g*NF + k0 + 8*lg);
            acc[nt] = __builtin_amdgcn_mfma_f32_16x16x32_bf16(af, bf, acc[nt], 0, 0, 0);
        }
    }

    float fsv[4] = {0,0,0,0}, fdv[4] = {0,0,0,0};
    #pragma unroll
    for (int nt = 0; nt < 4; nt++) {
        int g = w*64 + nt*16 + lr;
        float as = a[g], ad = a[NF + g];
        short4 hv;
        hv.x = f2bf(acc[nt][0]); hv.y = f2bf(acc[nt][1]);
        hv.z = f2bf(acc[nt][2]); hv.w = f2bf(acc[nt][3]);
        *(short4*)(hT + ((size_t)(b*NF + g))*NN + ib + lg*4) = hv;
        #pragma unroll
        for (int r = 0; r < 4; r++) { fsv[r] += acc[nt][r]*as; fdv[r] += acc[nt][r]*ad; }
    }
    #pragma unroll
    for (int mask = 1; mask < 16; mask <<= 1) {
        #pragma unroll
        for (int r = 0; r < 4; r++) {
            fsv[r] += __shfl_xor(fsv[r], mask);
            fdv[r] += __shfl_xor(fdv[r], mask);
        }
    }
    if (lr == 0) {
        #pragma unroll
        for (int r = 0; r < 4; r++) {
            atomicAdd(&fs_l[lg*4 + r], fsv[r]);
            atomicAdd(&fd_l[lg*4 + r], fdv[r]);
        }
    }
    __syncthreads();
    if (threadIdx.x < 16) {
        float fsu = fs_l[threadIdx.x], fdu = fd_l[threadIdx.x];
        fsrc[b*NN + ib + threadIdx.x] = fsu;
        fdst[b*NN + ib + threadIdx.x] = fdu;
        float wm = fdu;
        #pragma unroll
        for (int m = 1; m < 16; m <<= 1) wm = fmaxf(wm, __shfl_xor(wm, m));
        if (threadIdx.x == 0) atomicMax(maxfd + b, enc_ord(wm));
    }
}

// ---- fused masked-softmax + att@h + elu ----
// 512 blocks x 512 thr (8 waves). Block: 16 rows. Wave w: j in [w*256, w*256+256),
// ALL 256 f columns (16 n-tiles) -> each exp computed exactly once.
// Cross-wave combine: 3-stage LDS tree (64 KB) + LDS-atomic row sums.
__global__ __launch_bounds__(512,4) void gat_fused(
    const short* __restrict__ hT, const unsigned char* __restrict__ adjB,
    const float* __restrict__ fsrc, const float* __restrict__ fdst,
    const unsigned* __restrict__ maxfd, float* __restrict__ out)
{
    __shared__ float red[4][16*NF];
    __shared__ float ls_tot[16];
    const int w  = threadIdx.x >> 6;
    const int l  = threadIdx.x & 63;
    const int lr = l & 15, lg = l >> 4;
    const int b  = blockIdx.x >> 7;
    const int i0 = (blockIdx.x & 127) * 16;

    if (threadIdx.x < 16) ls_tot[threadIdx.x] = 0.f;
    __syncthreads();

    const int i = i0 + lr;
    const float fs = fsrc[b*NN + i];
    const float M  = fmaxf(fs + dec_ord(maxfd[b]), 0.f);  // >= row max, >= 0
    const float* fdb = fdst + b*NN;
    const unsigned char* arow = adjB + (size_t)(b*NN + i) * (NN/8);
    const short* hTb = hT + (size_t)b * NF * NN;

    f32x4 acc[16];
    #pragma unroll
    for (int t = 0; t < 16; t++) acc[t] = (f32x4){0.f,0.f,0.f,0.f};
    float lsum = 0.f;

    const int jbase = w * 256;
    #pragma unroll 2
    for (int it = 0; it < 8; ++it) {
        const int jb = jbase + it*32 + 8*lg;
        unsigned m8 = arow[jb >> 3];
        float4 fd0 = *(const float4*)(fdb + jb);
        float4 fd1 = *(const float4*)(fdb + jb + 4);
        float fda[8] = {fd0.x, fd0.y, fd0.z, fd0.w, fd1.x, fd1.y, fd1.z, fd1.w};
        bf16x8 af;
        #pragma unroll
        for (int e = 0; e < 8; e++) {
            float ev = fmaxf(fs + fda[e], 0.f);
            float pe = ((m8 >> e) & 1u) ? __expf(ev - M) : 0.f;
            lsum += pe;
            af[e] = f2bf(pe);
        }
        #pragma unroll
        for (int nt = 0; nt < 16; nt++) {
            bf16x8 bf = *(const bf16x8*)(hTb + (size_t)(nt*16 + lr)*NN + jb);
            acc[nt] = __builtin_amdgcn_mfma_f32_16x16x32_bf16(af, bf, acc[nt], 0, 0, 0);
        }
    }

    lsum += __shfl_xor(lsum, 16);
    lsum += __shfl_xor(lsum, 32);
    if (l < 16) atomicAdd(&ls_tot[l], lsum);

    auto red_store = [&](int slot) {
        #pragma unroll
        for (int nt = 0; nt < 16; nt++)
            #pragma unroll
            for (int r = 0; r < 4; r++)
                red[slot][(lg*4 + r)*NF + nt*16 + lr] = acc[nt][r];
    };
    auto red_add = [&](int slot) {
        #pragma unroll
        for (int nt = 0; nt < 16; nt++)
            #pragma unroll
            for (int r = 0; r < 4; r++)
                acc[nt][r] += red[slot][(lg*4 + r)*NF + nt*16 + lr];
    };

    if (w >= 4) red_store(w - 4);
    __syncthreads();
    if (w < 4) red_add(w);
    __syncthreads();
    if (w == 2 || w == 3) red_store(w - 2);
    __syncthreads();
    if (w < 2) red_add(w);
    __syncthreads();
    if (w == 1) red_store(0);
    __syncthreads();
    if (w == 0) { red_add(0); red_store(0); }
    __syncthreads();

    // cooperative epilogue: 512 thr x 8 f32 (vectorized LDS read + global store)
    const int t   = threadIdx.x;
    const int row = t >> 5;
    const int f8  = (t & 31) * 8;
    float lv = ls_tot[row];
    float rv = lv > 0.f ? 1.f / lv : 0.f;
    float4 v0 = *(const float4*)&red[0][row*NF + f8];
    float4 v1 = *(const float4*)&red[0][row*NF + f8 + 4];
    float o[8] = {v0.x, v0.y, v0.z, v0.w, v1.x, v1.y, v1.z, v1.w};
    #pragma unroll
    for (int e = 0; e < 8; e++) {
        float v = o[e] * rv;
        o[e] = v > 0.f ? v : expm1f(v);
    }
    float* op = out + (size_t)(b*NN + i0 + row)*NF + f8;
    *(float4*)op       = (float4){o[0], o[1], o[2], o[3]};
    *(float4*)(op + 4) = (float4){o[4], o[5], o[6], o[7]};
}

extern "C" void kernel_launch(void* const* d_in, const int* in_sizes, int n_in,
                              void* d_out, int out_size, void* d_ws, size_t ws_size,
                              hipStream_t stream) {
    const float* x   = (const float*)d_in[0];
    const int*   adj = (const int*)d_in[1];
    const float* W   = (const float*)d_in[2];
    const float* a   = (const float*)d_in[3];
    float* out = (float*)d_out;
    char* ws = (char*)d_ws;

    short* WT = (short*)(ws);                                        // 128 KB
    unsigned long long* adjP = (unsigned long long*)(ws + 0x20000);  // 2 MB
    short* hT = (short*)(ws + 0x220000);                             // 4 MB
    float* fsrc = (float*)(ws + 0x620000);                           // 32 KB
    float* fdst = (float*)(ws + 0x628000);                           // 32 KB
    unsigned* maxfd = (unsigned*)(ws + 0x630000);                    // 16 B

    const int prep_blocks = (NB*NN*NN)/256 + (NF*NF)/256 + 1;
    prep_kernel<<<prep_blocks, 256, 0, stream>>>(adj, W, WT, adjP, maxfd);
    h_kernel<<<(NB*NN)/16, 256, 0, stream>>>(x, WT, a, hT, fsrc, fdst, maxfd);
    gat_fused<<<NB*(NN/16), 512, 0, stream>>>(hT, (const unsigned char*)adjP,
                                              fsrc, fdst, maxfd, out);
}

// Round 3
// 72.527 us; speedup vs baseline: 1.9383x; 1.6550x over previous
//
#include <hip/hip_runtime.h>
#include <hip/hip_bf16.h>

#define NB 4
#define NN 2048
#define NF 256
#define TSTEPS 32   // NN / 64

using bf16x8 = __attribute__((ext_vector_type(8))) short;
using f32x4  = __attribute__((ext_vector_type(4))) float;
using i32x4  = __attribute__((ext_vector_type(4))) int;

__device__ __forceinline__ short f2bf(float f) {
    unsigned u = __float_as_uint(f);
    u += 0x7fffu + ((u >> 16) & 1u);   // RNE, finite inputs only
    return (short)(u >> 16);
}
__device__ __forceinline__ unsigned enc_ord(float f) {   // order-preserving f32->u32
    unsigned u = __float_as_uint(f);
    return (u & 0x80000000u) ? ~u : (u | 0x80000000u);
}
__device__ __forceinline__ float dec_ord(unsigned u) {
    unsigned i = (u & 0x80000000u) ? (u & 0x7fffffffu) : ~u;
    return __uint_as_float(i);
}
__device__ __forceinline__ void gll16(const void* g, void* l) {
    __builtin_amdgcn_global_load_lds(
        (const __attribute__((address_space(1))) unsigned int*)g,
        (__attribute__((address_space(3))) unsigned int*)l, 16, 0, 0);
}

// ---- prep: W->W^T bf16, zero maxfd (tiny) ----
__global__ __launch_bounds__(256) void prep_kernel(
    const float* __restrict__ W, short* __restrict__ WT, unsigned* __restrict__ maxfd)
{
    const int blk = blockIdx.x, tid = threadIdx.x;
    if (blk < (NF*NF)/256) {
        int t = blk*256 + tid;
        int g = t >> 8, f = t & 255;
        WT[t] = f2bf(W[f*NF + g]);        // WT[g][f] = W[f][g]
    } else if (tid < NB) {
        maxfd[tid] = 0u;
    }
}

// ---- h = x@W (bf16 MFMA); hT[b][g][i] bf16, f_src/f_dst, per-batch max(fdst) ----
__global__ __launch_bounds__(256,4) void h_kernel(
    const float* __restrict__ x, const short* __restrict__ WT, const float* __restrict__ a,
    short* __restrict__ hT, float* __restrict__ fsrc, float* __restrict__ fdst,
    unsigned* __restrict__ maxfd)
{
    __shared__ float fs_l[16], fd_l[16];
    const int w  = threadIdx.x >> 6;
    const int l  = threadIdx.x & 63;
    const int lr = l & 15, lg = l >> 4;
    const int b  = blockIdx.x >> 7;
    const int ib = (blockIdx.x & 127) * 16;

    if (threadIdx.x < 16) { fs_l[threadIdx.x] = 0.f; fd_l[threadIdx.x] = 0.f; }
    __syncthreads();

    f32x4 acc[4];
    #pragma unroll
    for (int t = 0; t < 4; t++) acc[t] = (f32x4){0.f,0.f,0.f,0.f};

    const float* xrow = x + (size_t)(b*NN + ib + lr) * NF;
    #pragma unroll
    for (int k0 = 0; k0 < NF; k0 += 32) {
        float4 v0 = *(const float4*)(xrow + k0 + 8*lg);
        float4 v1 = *(const float4*)(xrow + k0 + 8*lg + 4);
        bf16x8 af;
        af[0]=f2bf(v0.x); af[1]=f2bf(v0.y); af[2]=f2bf(v0.z); af[3]=f2bf(v0.w);
        af[4]=f2bf(v1.x); af[5]=f2bf(v1.y); af[6]=f2bf(v1.z); af[7]=f2bf(v1.w);
        #pragma unroll
        for (int nt = 0; nt < 4; nt++) {
            int g = w*64 + nt*16 + lr;
            bf16x8 bf = *(const bf16x8*)(WT + (size_t)g*NF + k0 + 8*lg);
            acc[nt] = __builtin_amdgcn_mfma_f32_16x16x32_bf16(af, bf, acc[nt], 0, 0, 0);
        }
    }

    float fsv[4] = {0,0,0,0}, fdv[4] = {0,0,0,0};
    #pragma unroll
    for (int nt = 0; nt < 4; nt++) {
        int g = w*64 + nt*16 + lr;
        float as = a[g], ad = a[NF + g];
        short4 hv;
        hv.x = f2bf(acc[nt][0]); hv.y = f2bf(acc[nt][1]);
        hv.z = f2bf(acc[nt][2]); hv.w = f2bf(acc[nt][3]);
        *(short4*)(hT + ((size_t)(b*NF + g))*NN + ib + lg*4) = hv;
        #pragma unroll
        for (int r = 0; r < 4; r++) { fsv[r] += acc[nt][r]*as; fdv[r] += acc[nt][r]*ad; }
    }
    #pragma unroll
    for (int mask = 1; mask < 16; mask <<= 1) {
        #pragma unroll
        for (int r = 0; r < 4; r++) {
            fsv[r] += __shfl_xor(fsv[r], mask);
            fdv[r] += __shfl_xor(fdv[r], mask);
        }
    }
    if (lr == 0) {
        #pragma unroll
        for (int r = 0; r < 4; r++) {
            atomicAdd(&fs_l[lg*4 + r], fsv[r]);
            atomicAdd(&fd_l[lg*4 + r], fdv[r]);
        }
    }
    __syncthreads();
    if (threadIdx.x < 16) {
        float fsu = fs_l[threadIdx.x], fdu = fd_l[threadIdx.x];
        fsrc[b*NN + ib + threadIdx.x] = fsu;
        fdst[b*NN + ib + threadIdx.x] = fdu;
        float wm = fdu;
        #pragma unroll
        for (int m = 1; m < 16; m <<= 1) wm = fmaxf(wm, __shfl_xor(wm, m));
        if (threadIdx.x == 0) atomicMax(maxfd + b, enc_ord(wm));
    }
}

// ---- fused: adj->mask + masked softmax + att@h + elu, LDS-pipelined ----
// grid 256 (1 block/CU), 512 thr (8 waves). Block: 32 rows, all 256 f, j-loop BK=64.
// Waves: fq = w&3 (64-f slice), kt = w>>2 (32-j half of each step).
// B-tile (256f x 64j bf16, 32KB) tri-buffered via global_load_lds, XOR-swizzled src.
// P-tile (32 x 64 bf16, 4KB) computed cooperatively (1 exp per (i,j), no redundancy).
__global__ __launch_bounds__(512,2) void gat_fused(
    const short* __restrict__ hT, const int* __restrict__ adj,
    const float* __restrict__ fsrc, const float* __restrict__ fdst,
    const unsigned* __restrict__ maxfd, float* __restrict__ out)
{
    __shared__ __align__(16) char smem[3*32768 + 4096 + 128];
    char* Pbuf = smem + 3*32768;
    float* ls  = (float*)(smem + 3*32768 + 4096);

    const int tid = threadIdx.x;
    const int w = tid >> 6, l = tid & 63, lr = l & 15, lg = l >> 4;
    const int fq = w & 3, kt = w >> 2;
    const int blk = blockIdx.x, b = blk >> 6, i0 = (blk & 63) * 32;

    // P-thread coords: thread owns (row prow, j-slice pc*4..pc*4+3) each step
    const int prow = tid >> 4, pc = tid & 15;
    const int pig = b*NN + i0 + prow;
    const float pfs = fsrc[pig];
    const float M = fmaxf(pfs + dec_ord(maxfd[b]), 0.f);   // per-row safe max bound
    const int*   adjrow = adj + (size_t)pig * NN + pc*4;
    const float* fdb    = fdst + b*NN + pc*4;
    const short* hTb    = hT + (size_t)b * NF * NN;

    f32x4 acc[2][4];
    #pragma unroll
    for (int a1 = 0; a1 < 2; ++a1)
        #pragma unroll
        for (int a2 = 0; a2 < 4; ++a2) acc[a1][a2] = (f32x4){0.f,0.f,0.f,0.f};
    float lsum_r = 0.f;

    auto STAGE = [&](int step) {   // stage hT[0:256][step*64 : +64] into slot step%3
        const int slot = step % 3;
        #pragma unroll
        for (int it = 0; it < 4; ++it) {
            int s = it*512 + w*64 + l;             // 16B chunk id, 2048 total
            int f = s >> 3, c = s & 7;
            const short* src = hTb + (size_t)f*NN + (step << 6) + ((c ^ (f & 7)) << 3);
            gll16(src, smem + slot*32768 + (it*512 + w*64)*16);   // uniform base + lane*16
        }
    };
    auto LOADPF = [&](int step, i32x4& av, f32x4& fv) {  // issued AFTER STAGE of same step
        av = __builtin_nontemporal_load((const i32x4*)(adjrow + (step << 6)));
        fv = *(const f32x4*)(fdb + (step << 6));
    };

    auto ITER = [&](int t, i32x4& av, f32x4& fv) {
        // ---- phase A: cooperative P(t) ----
        {
            float pv[4];
            #pragma unroll
            for (int e = 0; e < 4; ++e) {
                float ev = fmaxf(pfs + fv[e], 0.f);
                float pe = (av[e] > 0) ? __expf(ev - M) : 0.f;
                lsum_r += pe;
                pv[e] = pe;
            }
            short4 ph;
            ph.x = f2bf(pv[0]); ph.y = f2bf(pv[1]); ph.z = f2bf(pv[2]); ph.w = f2bf(pv[3]);
            *(short4*)(Pbuf + prow*128 + (((pc >> 1) ^ (prow & 7)) << 4) + ((pc & 1) << 3)) = ph;
        }
        // BAR1: P visible (consuming av above also drained this wave's gll(t) via
        // in-order vmcnt — adj(t) was issued after gll(t))
        __builtin_amdgcn_sched_barrier(0);
        asm volatile("s_waitcnt lgkmcnt(0)" ::: "memory");
        __builtin_amdgcn_s_barrier();
        __builtin_amdgcn_sched_barrier(0);
        // ---- phase B: prefetch t+2, then MFMA on tile t ----
        if (t + 2 < TSTEPS) {
            STAGE(t + 2);
            __builtin_amdgcn_sched_barrier(0);   // pin: gll before adj/fd (in-order chain)
            LOADPF(t + 2, av, fv);
        }
        const char* Bslot = smem + (t % 3) * 32768;
        bf16x8 af[2];
        #pragma unroll
        for (int rg = 0; rg < 2; ++rg) {
            int pr = rg*16 + lr;
            af[rg] = *(const bf16x8*)(Pbuf + pr*128 + ((((kt << 2) | lg) ^ (pr & 7)) << 4));
        }
        #pragma unroll
        for (int nt2 = 0; nt2 < 4; ++nt2) {
            int f = (fq*4 + nt2)*16 + lr;
            bf16x8 bf = *(const bf16x8*)(Bslot + f*128 + ((((kt << 2) | lg) ^ (f & 7)) << 4));
            acc[0][nt2] = __builtin_amdgcn_mfma_f32_16x16x32_bf16(af[0], bf, acc[0][nt2], 0, 0, 0);
            acc[1][nt2] = __builtin_amdgcn_mfma_f32_16x16x32_bf16(af[1], bf, acc[1][nt2], 0, 0, 0);
        }
        // BAR2: protect P (WAR) and B slot rotation
        __builtin_amdgcn_sched_barrier(0);
        __builtin_amdgcn_s_barrier();
        __builtin_amdgcn_sched_barrier(0);
    };

    // prologue: 2-deep pipeline
    i32x4 adj0, adj1; f32x4 fd0, fd1;
    STAGE(0); __builtin_amdgcn_sched_barrier(0); LOADPF(0, adj0, fd0);
    __builtin_amdgcn_sched_barrier(0);
    STAGE(1); __builtin_amdgcn_sched_barrier(0); LOADPF(1, adj1, fd1);

    for (int t2 = 0; t2 < TSTEPS; t2 += 2) {
        ITER(t2,     adj0, fd0);
        ITER(t2 + 1, adj1, fd1);
    }

    // ---- epilogue ----
    #pragma unroll
    for (int m = 1; m < 16; m <<= 1) lsum_r += __shfl_xor(lsum_r, m);
    if ((tid & 15) == 0) ls[tid >> 4] = lsum_r;
    __syncthreads();

    float* red = (float*)smem;   // [32][257] f32, aliases staging buffer (done)
    if (kt == 1) {
        #pragma unroll
        for (int rg = 0; rg < 2; ++rg)
            #pragma unroll
            for (int nt2 = 0; nt2 < 4; ++nt2)
                #pragma unroll
                for (int r = 0; r < 4; ++r)
                    red[(rg*16 + lg*4 + r)*257 + (fq*4 + nt2)*16 + lr] = acc[rg][nt2][r];
    }
    __syncthreads();
    if (kt == 0) {
        #pragma unroll
        for (int rg = 0; rg < 2; ++rg)
            #pragma unroll
            for (int nt2 = 0; nt2 < 4; ++nt2)
                #pragma unroll
                for (int r = 0; r < 4; ++r) {
                    int row = rg*16 + lg*4 + r;
                    int fcol = (fq*4 + nt2)*16 + lr;
                    float v = acc[rg][nt2][r] + red[row*257 + fcol];
                    float lv = ls[row];
                    float rv = lv > 0.f ? 1.f / lv : 0.f;
                    v *= rv;
                    v = v > 0.f ? v : expm1f(v);
                    out[((size_t)(b*NN + i0 + row))*NF + fcol] = v;
                }
    }
}

extern "C" void kernel_launch(void* const* d_in, const int* in_sizes, int n_in,
                              void* d_out, int out_size, void* d_ws, size_t ws_size,
                              hipStream_t stream) {
    const float* x   = (const float*)d_in[0];
    const int*   adj = (const int*)d_in[1];
    const float* W   = (const float*)d_in[2];
    const float* a   = (const float*)d_in[3];
    float* out = (float*)d_out;
    char* ws = (char*)d_ws;

    short* WT      = (short*)(ws);                    // 128 KB
    short* hT      = (short*)(ws + 0x20000);          // 4 MB
    float* fsrc    = (float*)(ws + 0x420000);         // 32 KB
    float* fdst    = (float*)(ws + 0x428000);         // 32 KB
    unsigned* maxfd = (unsigned*)(ws + 0x430000);     // 16 B

    prep_kernel<<<(NF*NF)/256 + 1, 256, 0, stream>>>(W, WT, maxfd);
    h_kernel<<<(NB*NN)/16, 256, 0, stream>>>(x, WT, a, hT, fsrc, fdst, maxfd);
    gat_fused<<<NB*(NN/32), 512, 0, stream>>>(hT, adj, fsrc, fdst, maxfd, out);
}